// Round 6
// baseline (517.805 us; speedup 1.0000x reference)
//
#include <hip/hip_runtime.h>
#include <cstdint>
#include <cmath>

#define NLVL 16
#define NDENSE 5
#define FBLK 1024u
// Levels 0+1 are contiguous from emb[0]: 4920 + 13824 = 18744 entries.
#define TAB_ENTRIES 18744u
// LDS floats: max(staged table 2*18744+pad, transpose 1024*33=33792) -> 37504 floats
#define LDS_FLOATS 37504u
#define LDS_BYTES (LDS_FLOATS * 4u)   // 150016 B <= 160 KiB

typedef float v2f __attribute__((ext_vector_type(2)));
typedef float v4f __attribute__((ext_vector_type(4)));
typedef float v4f8 __attribute__((ext_vector_type(4), aligned(8)));  // 8B-aligned float4

struct Params {
    float    scale[NLVL];
    uint32_t side[NLVL];
    uint32_t offset[NLVL];
    uint32_t hashed[NLVL];
};

struct DenseParams {
    float    scale[NDENSE];
    uint32_t side[NDENSE];
    uint32_t offset[NDENSE];
};

__device__ __forceinline__ uint32_t umin32(uint32_t a, uint32_t b) { return a < b ? a : b; }

// Hashed-level corner pair: adjacent even/odd pair iff c0a even -> one aligned
// dwordx4 serves both; else predicated v2f for corner b.
__device__ __forceinline__ void pair_load(const float* __restrict__ embf,
                                          uint32_t ia, uint32_t ib,
                                          v2f& va, v2f& vb) {
    const v4f q = *(const v4f*)(embf + 2u * (ia & ~1u));
    v2f lo; lo.x = q.x; lo.y = q.y;
    v2f hi; hi.x = q.z; hi.y = q.w;
    va = (ia & 1u) ? hi : lo;
    if ((ia ^ ib) > 1u) {
        vb = *(const v2f*)(embf + 2u * ib);   // predicated: only unpaired lanes
    } else {
        vb = (ib & 1u) ? hi : lo;
    }
}

// Dense-level x-pair from GLOBAL: contiguous (ib = ia+1, or clamped = ia).
__device__ __forceinline__ void dense_pair_load(const float* __restrict__ embf,
                                                uint32_t ia, uint32_t clamped,
                                                v2f& va, v2f& vb) {
    const v4f8 q = *(const v4f8*)(embf + 2u * ia);
    va.x = q.x; va.y = q.y;
    v2f hi; hi.x = q.z; hi.y = q.w;
    vb = clamped ? va : hi;
}

// Full per-point hashed-level evaluation (indices + 6 avg gathers + weights).
__device__ __forceinline__ v2f hash_point(const float* __restrict__ embf,
                                          float x, float y, float z,
                                          float scale, uint32_t side, uint32_t off) {
    float p0 = x * scale + 0.5f, p1 = y * scale + 0.5f, p2 = z * scale + 0.5f;
    float fl0 = floorf(p0), fl1 = floorf(p1), fl2 = floorf(p2);
    float f0 = p0 - fl0, f1 = p1 - fl1, f2 = p2 - fl2;
    uint32_t g0 = (uint32_t)fl0, g1 = (uint32_t)fl1, g2 = (uint32_t)fl2;

    const uint32_t smax = side - 1u;
    uint32_t c0a = umin32(g0, smax), c0b = umin32(g0 + 1u, smax);
    uint32_t c1a = umin32(g1, smax), c1b = umin32(g1 + 1u, smax);
    uint32_t c2a = umin32(g2, smax), c2b = umin32(g2 + 1u, smax);

    const uint32_t h1a = c1a * 2654435761u, h1b = c1b * 2654435761u;
    const uint32_t h2a = c2a * 805459861u,  h2b = c2b * 805459861u;
    const uint32_t idx0 = ((c0a ^ h1a ^ h2a) & 0x7FFFFu) + off;
    const uint32_t idx1 = ((c0a ^ h1a ^ h2b) & 0x7FFFFu) + off;
    const uint32_t idx2 = ((c0a ^ h1b ^ h2a) & 0x7FFFFu) + off;
    const uint32_t idx3 = ((c0a ^ h1b ^ h2b) & 0x7FFFFu) + off;
    const uint32_t idx4 = ((c0b ^ h1a ^ h2a) & 0x7FFFFu) + off;
    const uint32_t idx5 = ((c0b ^ h1a ^ h2b) & 0x7FFFFu) + off;
    const uint32_t idx6 = ((c0b ^ h1b ^ h2a) & 0x7FFFFu) + off;
    const uint32_t idx7 = ((c0b ^ h1b ^ h2b) & 0x7FFFFu) + off;

    v2f v0, v1, v2, v3, v4, v5, v6, v7;
    pair_load(embf, idx0, idx4, v0, v4);
    pair_load(embf, idx1, idx5, v1, v5);
    pair_load(embf, idx2, idx6, v2, v6);
    pair_load(embf, idx3, idx7, v3, v7);

    const float w0a = 1.0f - f0, w0b = f0;
    const float w1a = 1.0f - f1, w1b = f1;
    const float w2a = 1.0f - f2, w2b = f2;
    return (w0a * w1a * w2a) * v0 + (w0a * w1a * w2b) * v1
         + (w0a * w1b * w2a) * v2 + (w0a * w1b * w2b) * v3
         + (w0b * w1a * w2a) * v4 + (w0b * w1a * w2b) * v5
         + (w0b * w1b * w2a) * v6 + (w0b * w1b * w2b) * v7;
}

// ---------- Phase kernel: one hashed level, 2 points/thread (double MLP) ----------
__global__ __launch_bounds__(256) void hash_level_kernel2(
    const float* __restrict__ in, const float* __restrict__ embf,
    v2f* __restrict__ wsl, float scale, uint32_t side, uint32_t off)
{
    const uint32_t iA = blockIdx.x * 512u + threadIdx.x;
    const uint32_t iB = iA + 256u;
    // nt inputs: keep the 4-MB table exclusively L2-resident
    const float xA = __builtin_nontemporal_load(in + 3u * iA + 0u);
    const float yA = __builtin_nontemporal_load(in + 3u * iA + 1u);
    const float zA = __builtin_nontemporal_load(in + 3u * iA + 2u);
    const float xB = __builtin_nontemporal_load(in + 3u * iB + 0u);
    const float yB = __builtin_nontemporal_load(in + 3u * iB + 1u);
    const float zB = __builtin_nontemporal_load(in + 3u * iB + 2u);

    const v2f rA = hash_point(embf, xA, yA, zA, scale, side, off);
    const v2f rB = hash_point(embf, xB, yB, zB, scale, side, off);

    __builtin_nontemporal_store(rA, wsl + iA);
    __builtin_nontemporal_store(rB, wsl + iB);
}

// ---------- Phase kernel: 1 point/thread (fallback for odd sizes) ----------
__global__ __launch_bounds__(256) void hash_level_kernel(
    const float* __restrict__ in, const float* __restrict__ embf,
    v2f* __restrict__ wsl, float scale, uint32_t side, uint32_t off, uint32_t npts)
{
    const uint32_t i = blockIdx.x * 256u + threadIdx.x;
    if (i >= npts) return;
    const float x = __builtin_nontemporal_load(in + 3u * i + 0u);
    const float y = __builtin_nontemporal_load(in + 3u * i + 1u);
    const float z = __builtin_nontemporal_load(in + 3u * i + 2u);
    const v2f r = hash_point(embf, x, y, z, scale, side, off);
    __builtin_nontemporal_store(r, wsl + i);
}

// ---------- Finalize: LDS-staged levels 0-1, global levels 2-4, ws 5-15 -> out ----------
__global__ __launch_bounds__(1024, 4) void finalize_kernel(
    const float* __restrict__ in, const float* __restrict__ embf,
    const v2f* __restrict__ ws, float* __restrict__ out,
    uint32_t npts, DenseParams P)
{
    extern __shared__ float lds[];
    const uint32_t t = threadIdx.x;
    const uint32_t i = blockIdx.x * FBLK + t;

    // Phase A: stage emb[0 .. TAB_ENTRIES) (levels 0+1, contiguous) into LDS.
    {
        const v4f* src4 = (const v4f*)embf;
        v4f* dst4 = (v4f*)lds;
        #pragma unroll
        for (uint32_t j = 0; j < 10; ++j) {
            const uint32_t k = j * FBLK + t;
            if (k < LDS_FLOATS / 4u) dst4[k] = src4[k];
        }
    }

    const float x = __builtin_nontemporal_load(in + 3u * i + 0u);
    const float y = __builtin_nontemporal_load(in + 3u * i + 1u);
    const float z = __builtin_nontemporal_load(in + 3u * i + 2u);

    __syncthreads();

    float res[32];   // fully static-indexed (unrolled) -> registers

    // dense levels; 0-1 from LDS, 2-4 from global (L2-resident)
    #pragma unroll
    for (int l = 0; l < NDENSE; ++l) {
        const float scale = P.scale[l];
        const uint32_t side = P.side[l];
        const uint32_t off  = P.offset[l];

        float p0 = x * scale + 0.5f, p1 = y * scale + 0.5f, p2 = z * scale + 0.5f;
        float fl0 = floorf(p0), fl1 = floorf(p1), fl2 = floorf(p2);
        float f0 = p0 - fl0, f1 = p1 - fl1, f2 = p2 - fl2;
        uint32_t g0 = (uint32_t)fl0, g1 = (uint32_t)fl1, g2 = (uint32_t)fl2;

        const uint32_t smax = side - 1u;
        uint32_t c0a = umin32(g0, smax);
        const uint32_t clamped = (c0a == smax) ? 1u : 0u;   // c0b == c0a
        uint32_t c1a = umin32(g1, smax), c1b = umin32(g1 + 1u, smax);
        uint32_t c2a = umin32(g2, smax), c2b = umin32(g2 + 1u, smax);

        const uint32_t s2 = side * side;
        const uint32_t ia0 = c0a + c1a * side + c2a * s2 + off;
        const uint32_t ia1 = c0a + c1a * side + c2b * s2 + off;
        const uint32_t ia2 = c0a + c1b * side + c2a * s2 + off;
        const uint32_t ia3 = c0a + c1b * side + c2b * s2 + off;

        v2f v0, v1, v2, v3, v4, v5, v6, v7;
        if (l < 2) {
            v0 = *(const v2f*)(lds + 2u * ia0);
            v4 = clamped ? v0 : *(const v2f*)(lds + 2u * ia0 + 2u);
            v1 = *(const v2f*)(lds + 2u * ia1);
            v5 = clamped ? v1 : *(const v2f*)(lds + 2u * ia1 + 2u);
            v2 = *(const v2f*)(lds + 2u * ia2);
            v6 = clamped ? v2 : *(const v2f*)(lds + 2u * ia2 + 2u);
            v3 = *(const v2f*)(lds + 2u * ia3);
            v7 = clamped ? v3 : *(const v2f*)(lds + 2u * ia3 + 2u);
        } else {
            dense_pair_load(embf, ia0, clamped, v0, v4);
            dense_pair_load(embf, ia1, clamped, v1, v5);
            dense_pair_load(embf, ia2, clamped, v2, v6);
            dense_pair_load(embf, ia3, clamped, v3, v7);
        }

        const float w0a = 1.0f - f0, w0b = f0;
        const float w1a = 1.0f - f1, w1b = f1;
        const float w2a = 1.0f - f2, w2b = f2;
        v2f r = (w0a * w1a * w2a) * v0 + (w0a * w1a * w2b) * v1
              + (w0a * w1b * w2a) * v2 + (w0a * w1b * w2b) * v3
              + (w0b * w1a * w2a) * v4 + (w0b * w1a * w2b) * v5
              + (w0b * w1b * w2a) * v6 + (w0b * w1b * w2b) * v7;
        res[2 * l]     = r.x;
        res[2 * l + 1] = r.y;
    }

    // hashed levels 5..15 from workspace (coalesced)
    #pragma unroll
    for (int l = NDENSE; l < NLVL; ++l) {
        v2f r = __builtin_nontemporal_load(ws + (size_t)(l - NDENSE) * npts + i);
        res[2 * l]     = r.x;
        res[2 * l + 1] = r.y;
    }

    // Phase B: reuse LDS as [1024][33] transpose buffer
    __syncthreads();
    {
        float* row = lds + t * 33u;
        #pragma unroll
        for (int k = 0; k < 32; ++k) row[k] = res[k];   // stride 33: conflict-free
    }
    __syncthreads();

    // coalesced output: block's 128 KB chunk written contiguously
    float* obase = out + (size_t)blockIdx.x * FBLK * 32u;
    #pragma unroll
    for (uint32_t k = 0; k < 8; ++k) {
        const uint32_t f = k * 4096u + t * 4u;          // float idx in chunk
        const uint32_t p = f >> 5, c = f & 31u;
        const float* src = lds + p * 33u + c;
        v4f q; q.x = src[0]; q.y = src[1]; q.z = src[2]; q.w = src[3];
        __builtin_nontemporal_store(q, (v4f*)(obase + f));
    }
}

// ---------- Fallback: monolithic kernel (used if ws too small / odd sizes) ----------
__global__ __launch_bounds__(256) void grid_encode_mono(
    const float* __restrict__ in, const float* __restrict__ emb,
    float* __restrict__ out, uint32_t npts, Params P)
{
    const uint32_t i = blockIdx.x * 256u + threadIdx.x;
    if (i >= npts) return;
    const float x = in[3u * i + 0u], y = in[3u * i + 1u], z = in[3u * i + 2u];
    const v2f* e2 = (const v2f*)emb;
    float* outp = out + (size_t)i * 32u;

    #pragma unroll 1
    for (int l = 0; l < NLVL; ++l) {
        const float scale = P.scale[l];
        const uint32_t side = P.side[l], off = P.offset[l], hashed = P.hashed[l];
        float p0 = x * scale + 0.5f, p1 = y * scale + 0.5f, p2 = z * scale + 0.5f;
        float fl0 = floorf(p0), fl1 = floorf(p1), fl2 = floorf(p2);
        float f0 = p0 - fl0, f1 = p1 - fl1, f2 = p2 - fl2;
        uint32_t g0 = (uint32_t)fl0, g1 = (uint32_t)fl1, g2 = (uint32_t)fl2;
        const uint32_t smax = side - 1u;
        uint32_t c0a = umin32(g0, smax), c0b = umin32(g0 + 1u, smax);
        uint32_t c1a = umin32(g1, smax), c1b = umin32(g1 + 1u, smax);
        uint32_t c2a = umin32(g2, smax), c2b = umin32(g2 + 1u, smax);
        uint32_t idx0, idx1, idx2, idx3, idx4, idx5, idx6, idx7;
        if (hashed) {
            const uint32_t h1a = c1a * 2654435761u, h1b = c1b * 2654435761u;
            const uint32_t h2a = c2a * 805459861u,  h2b = c2b * 805459861u;
            idx0 = ((c0a ^ h1a ^ h2a) & 0x7FFFFu) + off;
            idx1 = ((c0a ^ h1a ^ h2b) & 0x7FFFFu) + off;
            idx2 = ((c0a ^ h1b ^ h2a) & 0x7FFFFu) + off;
            idx3 = ((c0a ^ h1b ^ h2b) & 0x7FFFFu) + off;
            idx4 = ((c0b ^ h1a ^ h2a) & 0x7FFFFu) + off;
            idx5 = ((c0b ^ h1a ^ h2b) & 0x7FFFFu) + off;
            idx6 = ((c0b ^ h1b ^ h2a) & 0x7FFFFu) + off;
            idx7 = ((c0b ^ h1b ^ h2b) & 0x7FFFFu) + off;
        } else {
            const uint32_t s2 = side * side;
            const uint32_t b1a = c1a * side, b1b = c1b * side;
            const uint32_t b2a = c2a * s2,   b2b = c2b * s2;
            idx0 = (c0a + b1a + b2a) + off; idx1 = (c0a + b1a + b2b) + off;
            idx2 = (c0a + b1b + b2a) + off; idx3 = (c0a + b1b + b2b) + off;
            idx4 = (c0b + b1a + b2a) + off; idx5 = (c0b + b1a + b2b) + off;
            idx6 = (c0b + b1b + b2a) + off; idx7 = (c0b + b1b + b2b) + off;
        }
        const v2f v0 = e2[idx0], v1 = e2[idx1], v2 = e2[idx2], v3 = e2[idx3];
        const v2f v4 = e2[idx4], v5 = e2[idx5], v6 = e2[idx6], v7 = e2[idx7];
        const float w0a = 1.0f - f0, w0b = f0;
        const float w1a = 1.0f - f1, w1b = f1;
        const float w2a = 1.0f - f2, w2b = f2;
        v2f r = (w0a*w1a*w2a) * v0 + (w0a*w1a*w2b) * v1 + (w0a*w1b*w2a) * v2 + (w0a*w1b*w2b) * v3
              + (w0b*w1a*w2a) * v4 + (w0b*w1a*w2b) * v5 + (w0b*w1b*w2a) * v6 + (w0b*w1b*w2b) * v7;
        *(v2f*)(outp + 2 * l) = r;
    }
}

extern "C" void kernel_launch(void* const* d_in, const int* in_sizes, int n_in,
                              void* d_out, int out_size, void* d_ws, size_t ws_size,
                              hipStream_t stream) {
    const float* inputs = (const float*)d_in[0];
    const float* emb    = (const float*)d_in[1];
    float* out          = (float*)d_out;

    // Mirror GridEncoder.__init__ level config in double precision (matches numpy).
    Params P;
    DenseParams DP;
    const double PLS = exp2(log2(2048.0 / 16.0) / 15.0);
    uint64_t off = 0;
    for (int l = 0; l < NLVL; ++l) {
        const double s = 16.0 * pow(PLS, (double)l);
        const uint32_t side = (uint32_t)ceil(s) + 1u;
        const uint64_t s3 = (uint64_t)side * side * side;
        uint64_t params = s3 < (1ull << 19) ? s3 : (1ull << 19);
        params = (params + 7ull) / 8ull * 8ull;
        P.scale[l]  = (float)(s - 1.0);
        P.side[l]   = side;
        P.offset[l] = (uint32_t)off;
        P.hashed[l] = (s3 > params) ? 1u : 0u;
        if (l < NDENSE) { DP.scale[l] = P.scale[l]; DP.side[l] = P.side[l]; DP.offset[l] = P.offset[l]; }
        off += params;
    }

    const uint32_t npts = (uint32_t)(in_sizes[0] / 3);
    const size_t ws_needed = (size_t)(NLVL - NDENSE) * npts * sizeof(v2f);

    if (ws_size >= ws_needed && (npts % FBLK) == 0u) {
        v2f* ws = (v2f*)d_ws;
        // hashed levels 5..15, one kernel each (temporal phasing for L2 residency)
        for (int l = NDENSE; l < NLVL; ++l) {
            hipLaunchKernelGGL(hash_level_kernel2, dim3(npts / 512u), dim3(256), 0, stream,
                               inputs, emb, ws + (size_t)(l - NDENSE) * npts,
                               P.scale[l], P.side[l], P.offset[l]);
        }
        // allow >64 KiB dynamic LDS (host-side attribute set; graph-capture-safe)
        static bool attr_set = [] {
            hipFuncSetAttribute(reinterpret_cast<const void*>(finalize_kernel),
                                hipFuncAttributeMaxDynamicSharedMemorySize, LDS_BYTES);
            return true;
        }();
        (void)attr_set;
        hipLaunchKernelGGL(finalize_kernel, dim3(npts / FBLK), dim3(FBLK), LDS_BYTES, stream,
                           inputs, emb, ws, out, npts, DP);
    } else {
        const uint32_t nblk = (npts + 255u) / 256u;
        hipLaunchKernelGGL(grid_encode_mono, dim3(nblk), dim3(256), 0, stream,
                           inputs, emb, out, npts, P);
    }
}

// Round 7
// 498.585 us; speedup vs baseline: 1.0386x; 1.0386x over previous
//
#include <hip/hip_runtime.h>
#include <cstdint>
#include <cmath>

#define NLVL 16
#define NDENSE 5
#define FBLK 1024u
// Levels 0+1 are contiguous from emb[0]: 4920 + 13824 = 18744 entries.
#define TAB_ENTRIES 18744u
// LDS floats: max(staged table 2*18744+pad, transpose 1024*33=33792) -> 37504 floats
#define LDS_FLOATS 37504u
#define LDS_BYTES (LDS_FLOATS * 4u)   // 150016 B <= 160 KiB

typedef float v2f __attribute__((ext_vector_type(2)));
typedef float v4f __attribute__((ext_vector_type(4)));
typedef float v4f8 __attribute__((ext_vector_type(4), aligned(8)));  // 8B-aligned float4

struct Params {
    float    scale[NLVL];
    uint32_t side[NLVL];
    uint32_t offset[NLVL];
    uint32_t hashed[NLVL];
};

struct DenseParams {
    float    scale[NDENSE];
    uint32_t side[NDENSE];
    uint32_t offset[NDENSE];
};

__device__ __forceinline__ uint32_t umin32(uint32_t a, uint32_t b) { return a < b ? a : b; }

// Hashed-level corner pair: adjacent even/odd pair iff c0a even -> one aligned
// dwordx4 serves both; else predicated v2f for corner b.
__device__ __forceinline__ void pair_load(const float* __restrict__ embf,
                                          uint32_t ia, uint32_t ib,
                                          v2f& va, v2f& vb) {
    const v4f q = *(const v4f*)(embf + 2u * (ia & ~1u));
    v2f lo; lo.x = q.x; lo.y = q.y;
    v2f hi; hi.x = q.z; hi.y = q.w;
    va = (ia & 1u) ? hi : lo;
    if ((ia ^ ib) > 1u) {
        vb = *(const v2f*)(embf + 2u * ib);   // predicated: only unpaired lanes
    } else {
        vb = (ib & 1u) ? hi : lo;
    }
}

// Dense-level x-pair from GLOBAL: contiguous (ib = ia+1, or clamped = ia).
__device__ __forceinline__ void dense_pair_load(const float* __restrict__ embf,
                                                uint32_t ia, uint32_t clamped,
                                                v2f& va, v2f& vb) {
    const v4f8 q = *(const v4f8*)(embf + 2u * ia);
    va.x = q.x; va.y = q.y;
    v2f hi; hi.x = q.z; hi.y = q.w;
    vb = clamped ? va : hi;
}

// Full per-point hashed-level evaluation (indices + 6 avg gathers + weights).
__device__ __forceinline__ v2f hash_point(const float* __restrict__ embf,
                                          float x, float y, float z,
                                          float scale, uint32_t side, uint32_t off) {
    float p0 = x * scale + 0.5f, p1 = y * scale + 0.5f, p2 = z * scale + 0.5f;
    float fl0 = floorf(p0), fl1 = floorf(p1), fl2 = floorf(p2);
    float f0 = p0 - fl0, f1 = p1 - fl1, f2 = p2 - fl2;
    uint32_t g0 = (uint32_t)fl0, g1 = (uint32_t)fl1, g2 = (uint32_t)fl2;

    const uint32_t smax = side - 1u;
    uint32_t c0a = umin32(g0, smax), c0b = umin32(g0 + 1u, smax);
    uint32_t c1a = umin32(g1, smax), c1b = umin32(g1 + 1u, smax);
    uint32_t c2a = umin32(g2, smax), c2b = umin32(g2 + 1u, smax);

    const uint32_t h1a = c1a * 2654435761u, h1b = c1b * 2654435761u;
    const uint32_t h2a = c2a * 805459861u,  h2b = c2b * 805459861u;
    const uint32_t idx0 = ((c0a ^ h1a ^ h2a) & 0x7FFFFu) + off;
    const uint32_t idx1 = ((c0a ^ h1a ^ h2b) & 0x7FFFFu) + off;
    const uint32_t idx2 = ((c0a ^ h1b ^ h2a) & 0x7FFFFu) + off;
    const uint32_t idx3 = ((c0a ^ h1b ^ h2b) & 0x7FFFFu) + off;
    const uint32_t idx4 = ((c0b ^ h1a ^ h2a) & 0x7FFFFu) + off;
    const uint32_t idx5 = ((c0b ^ h1a ^ h2b) & 0x7FFFFu) + off;
    const uint32_t idx6 = ((c0b ^ h1b ^ h2a) & 0x7FFFFu) + off;
    const uint32_t idx7 = ((c0b ^ h1b ^ h2b) & 0x7FFFFu) + off;

    v2f v0, v1, v2, v3, v4, v5, v6, v7;
    pair_load(embf, idx0, idx4, v0, v4);
    pair_load(embf, idx1, idx5, v1, v5);
    pair_load(embf, idx2, idx6, v2, v6);
    pair_load(embf, idx3, idx7, v3, v7);

    const float w0a = 1.0f - f0, w0b = f0;
    const float w1a = 1.0f - f1, w1b = f1;
    const float w2a = 1.0f - f2, w2b = f2;
    return (w0a * w1a * w2a) * v0 + (w0a * w1a * w2b) * v1
         + (w0a * w1b * w2a) * v2 + (w0a * w1b * w2b) * v3
         + (w0b * w1a * w2a) * v4 + (w0b * w1a * w2b) * v5
         + (w0b * w1b * w2a) * v6 + (w0b * w1b * w2b) * v7;
}

// ---------- Phase kernel: one hashed level, 2 points/thread (ILP experiment,
// CACHED input loads — round-6's nt-loads bypassed L2/L3 and regressed) ----------
__global__ __launch_bounds__(256) void hash_level_kernel2(
    const float* __restrict__ in, const float* __restrict__ embf,
    v2f* __restrict__ wsl, float scale, uint32_t side, uint32_t off)
{
    const uint32_t iA = blockIdx.x * 512u + threadIdx.x;
    const uint32_t iB = iA + 256u;
    const float xA = in[3u * iA + 0u];
    const float yA = in[3u * iA + 1u];
    const float zA = in[3u * iA + 2u];
    const float xB = in[3u * iB + 0u];
    const float yB = in[3u * iB + 1u];
    const float zB = in[3u * iB + 2u];

    const v2f rA = hash_point(embf, xA, yA, zA, scale, side, off);
    const v2f rB = hash_point(embf, xB, yB, zB, scale, side, off);

    __builtin_nontemporal_store(rA, wsl + iA);
    __builtin_nontemporal_store(rB, wsl + iB);
}

// ---------- Phase kernel: 1 point/thread (fallback for odd sizes) ----------
__global__ __launch_bounds__(256) void hash_level_kernel(
    const float* __restrict__ in, const float* __restrict__ embf,
    v2f* __restrict__ wsl, float scale, uint32_t side, uint32_t off, uint32_t npts)
{
    const uint32_t i = blockIdx.x * 256u + threadIdx.x;
    if (i >= npts) return;
    const float x = in[3u * i + 0u];
    const float y = in[3u * i + 1u];
    const float z = in[3u * i + 2u];
    const v2f r = hash_point(embf, x, y, z, scale, side, off);
    __builtin_nontemporal_store(r, wsl + i);
}

// ---------- Finalize: LDS-staged levels 0-1, global levels 2-4, ws 5-15 -> out ----------
// (exact round-5 version: 109 us known-good)
__global__ __launch_bounds__(1024, 4) void finalize_kernel(
    const float* __restrict__ in, const float* __restrict__ embf,
    const v2f* __restrict__ ws, float* __restrict__ out,
    uint32_t npts, DenseParams P)
{
    extern __shared__ float lds[];
    const uint32_t t = threadIdx.x;
    const uint32_t i = blockIdx.x * FBLK + t;

    // Phase A: stage emb[0 .. TAB_ENTRIES) (levels 0+1, contiguous) into LDS.
    {
        const v4f* src4 = (const v4f*)embf;
        v4f* dst4 = (v4f*)lds;
        #pragma unroll
        for (uint32_t j = 0; j < 10; ++j) {
            const uint32_t k = j * FBLK + t;
            if (k < LDS_FLOATS / 4u) dst4[k] = src4[k];
        }
    }

    const float x = in[3u * i + 0u];
    const float y = in[3u * i + 1u];
    const float z = in[3u * i + 2u];

    __syncthreads();

    float res[32];   // fully static-indexed (unrolled) -> registers

    // dense levels; 0-1 from LDS, 2-4 from global (L2-resident)
    #pragma unroll
    for (int l = 0; l < NDENSE; ++l) {
        const float scale = P.scale[l];
        const uint32_t side = P.side[l];
        const uint32_t off  = P.offset[l];

        float p0 = x * scale + 0.5f, p1 = y * scale + 0.5f, p2 = z * scale + 0.5f;
        float fl0 = floorf(p0), fl1 = floorf(p1), fl2 = floorf(p2);
        float f0 = p0 - fl0, f1 = p1 - fl1, f2 = p2 - fl2;
        uint32_t g0 = (uint32_t)fl0, g1 = (uint32_t)fl1, g2 = (uint32_t)fl2;

        const uint32_t smax = side - 1u;
        uint32_t c0a = umin32(g0, smax);
        const uint32_t clamped = (c0a == smax) ? 1u : 0u;   // c0b == c0a
        uint32_t c1a = umin32(g1, smax), c1b = umin32(g1 + 1u, smax);
        uint32_t c2a = umin32(g2, smax), c2b = umin32(g2 + 1u, smax);

        const uint32_t s2 = side * side;
        const uint32_t ia0 = c0a + c1a * side + c2a * s2 + off;
        const uint32_t ia1 = c0a + c1a * side + c2b * s2 + off;
        const uint32_t ia2 = c0a + c1b * side + c2a * s2 + off;
        const uint32_t ia3 = c0a + c1b * side + c2b * s2 + off;

        v2f v0, v1, v2, v3, v4, v5, v6, v7;
        if (l < 2) {
            v0 = *(const v2f*)(lds + 2u * ia0);
            v4 = clamped ? v0 : *(const v2f*)(lds + 2u * ia0 + 2u);
            v1 = *(const v2f*)(lds + 2u * ia1);
            v5 = clamped ? v1 : *(const v2f*)(lds + 2u * ia1 + 2u);
            v2 = *(const v2f*)(lds + 2u * ia2);
            v6 = clamped ? v2 : *(const v2f*)(lds + 2u * ia2 + 2u);
            v3 = *(const v2f*)(lds + 2u * ia3);
            v7 = clamped ? v3 : *(const v2f*)(lds + 2u * ia3 + 2u);
        } else {
            dense_pair_load(embf, ia0, clamped, v0, v4);
            dense_pair_load(embf, ia1, clamped, v1, v5);
            dense_pair_load(embf, ia2, clamped, v2, v6);
            dense_pair_load(embf, ia3, clamped, v3, v7);
        }

        const float w0a = 1.0f - f0, w0b = f0;
        const float w1a = 1.0f - f1, w1b = f1;
        const float w2a = 1.0f - f2, w2b = f2;
        v2f r = (w0a * w1a * w2a) * v0 + (w0a * w1a * w2b) * v1
              + (w0a * w1b * w2a) * v2 + (w0a * w1b * w2b) * v3
              + (w0b * w1a * w2a) * v4 + (w0b * w1a * w2b) * v5
              + (w0b * w1b * w2a) * v6 + (w0b * w1b * w2b) * v7;
        res[2 * l]     = r.x;
        res[2 * l + 1] = r.y;
    }

    // hashed levels 5..15 from workspace (coalesced)
    #pragma unroll
    for (int l = NDENSE; l < NLVL; ++l) {
        v2f r = __builtin_nontemporal_load(ws + (size_t)(l - NDENSE) * npts + i);
        res[2 * l]     = r.x;
        res[2 * l + 1] = r.y;
    }

    // Phase B: reuse LDS as [1024][33] transpose buffer
    __syncthreads();
    {
        float* row = lds + t * 33u;
        #pragma unroll
        for (int k = 0; k < 32; ++k) row[k] = res[k];   // stride 33: conflict-free
    }
    __syncthreads();

    // coalesced output: block's 128 KB chunk written contiguously
    float* obase = out + (size_t)blockIdx.x * FBLK * 32u;
    #pragma unroll
    for (uint32_t k = 0; k < 8; ++k) {
        const uint32_t f = k * 4096u + t * 4u;          // float idx in chunk
        const uint32_t p = f >> 5, c = f & 31u;
        const float* src = lds + p * 33u + c;
        v4f q; q.x = src[0]; q.y = src[1]; q.z = src[2]; q.w = src[3];
        __builtin_nontemporal_store(q, (v4f*)(obase + f));
    }
}

// ---------- Fallback: monolithic kernel (used if ws too small / odd sizes) ----------
__global__ __launch_bounds__(256) void grid_encode_mono(
    const float* __restrict__ in, const float* __restrict__ emb,
    float* __restrict__ out, uint32_t npts, Params P)
{
    const uint32_t i = blockIdx.x * 256u + threadIdx.x;
    if (i >= npts) return;
    const float x = in[3u * i + 0u], y = in[3u * i + 1u], z = in[3u * i + 2u];
    const v2f* e2 = (const v2f*)emb;
    float* outp = out + (size_t)i * 32u;

    #pragma unroll 1
    for (int l = 0; l < NLVL; ++l) {
        const float scale = P.scale[l];
        const uint32_t side = P.side[l], off = P.offset[l], hashed = P.hashed[l];
        float p0 = x * scale + 0.5f, p1 = y * scale + 0.5f, p2 = z * scale + 0.5f;
        float fl0 = floorf(p0), fl1 = floorf(p1), fl2 = floorf(p2);
        float f0 = p0 - fl0, f1 = p1 - fl1, f2 = p2 - fl2;
        uint32_t g0 = (uint32_t)fl0, g1 = (uint32_t)fl1, g2 = (uint32_t)fl2;
        const uint32_t smax = side - 1u;
        uint32_t c0a = umin32(g0, smax), c0b = umin32(g0 + 1u, smax);
        uint32_t c1a = umin32(g1, smax), c1b = umin32(g1 + 1u, smax);
        uint32_t c2a = umin32(g2, smax), c2b = umin32(g2 + 1u, smax);
        uint32_t idx0, idx1, idx2, idx3, idx4, idx5, idx6, idx7;
        if (hashed) {
            const uint32_t h1a = c1a * 2654435761u, h1b = c1b * 2654435761u;
            const uint32_t h2a = c2a * 805459861u,  h2b = c2b * 805459861u;
            idx0 = ((c0a ^ h1a ^ h2a) & 0x7FFFFu) + off;
            idx1 = ((c0a ^ h1a ^ h2b) & 0x7FFFFu) + off;
            idx2 = ((c0a ^ h1b ^ h2a) & 0x7FFFFu) + off;
            idx3 = ((c0a ^ h1b ^ h2b) & 0x7FFFFu) + off;
            idx4 = ((c0b ^ h1a ^ h2a) & 0x7FFFFu) + off;
            idx5 = ((c0b ^ h1a ^ h2b) & 0x7FFFFu) + off;
            idx6 = ((c0b ^ h1b ^ h2a) & 0x7FFFFu) + off;
            idx7 = ((c0b ^ h1b ^ h2b) & 0x7FFFFu) + off;
        } else {
            const uint32_t s2 = side * side;
            const uint32_t b1a = c1a * side, b1b = c1b * side;
            const uint32_t b2a = c2a * s2,   b2b = c2b * s2;
            idx0 = (c0a + b1a + b2a) + off; idx1 = (c0a + b1a + b2b) + off;
            idx2 = (c0a + b1b + b2a) + off; idx3 = (c0a + b1b + b2b) + off;
            idx4 = (c0b + b1a + b2a) + off; idx5 = (c0b + b1a + b2b) + off;
            idx6 = (c0b + b1b + b2a) + off; idx7 = (c0b + b1b + b2b) + off;
        }
        const v2f v0 = e2[idx0], v1 = e2[idx1], v2 = e2[idx2], v3 = e2[idx3];
        const v2f v4 = e2[idx4], v5 = e2[idx5], v6 = e2[idx6], v7 = e2[idx7];
        const float w0a = 1.0f - f0, w0b = f0;
        const float w1a = 1.0f - f1, w1b = f1;
        const float w2a = 1.0f - f2, w2b = f2;
        v2f r = (w0a*w1a*w2a) * v0 + (w0a*w1a*w2b) * v1 + (w0a*w1b*w2a) * v2 + (w0a*w1b*w2b) * v3
              + (w0b*w1a*w2a) * v4 + (w0b*w1a*w2b) * v5 + (w0b*w1b*w2a) * v6 + (w0b*w1b*w2b) * v7;
        *(v2f*)(outp + 2 * l) = r;
    }
}

extern "C" void kernel_launch(void* const* d_in, const int* in_sizes, int n_in,
                              void* d_out, int out_size, void* d_ws, size_t ws_size,
                              hipStream_t stream) {
    const float* inputs = (const float*)d_in[0];
    const float* emb    = (const float*)d_in[1];
    float* out          = (float*)d_out;

    // Mirror GridEncoder.__init__ level config in double precision (matches numpy).
    Params P;
    DenseParams DP;
    const double PLS = exp2(log2(2048.0 / 16.0) / 15.0);
    uint64_t off = 0;
    for (int l = 0; l < NLVL; ++l) {
        const double s = 16.0 * pow(PLS, (double)l);
        const uint32_t side = (uint32_t)ceil(s) + 1u;
        const uint64_t s3 = (uint64_t)side * side * side;
        uint64_t params = s3 < (1ull << 19) ? s3 : (1ull << 19);
        params = (params + 7ull) / 8ull * 8ull;
        P.scale[l]  = (float)(s - 1.0);
        P.side[l]   = side;
        P.offset[l] = (uint32_t)off;
        P.hashed[l] = (s3 > params) ? 1u : 0u;
        if (l < NDENSE) { DP.scale[l] = P.scale[l]; DP.side[l] = P.side[l]; DP.offset[l] = P.offset[l]; }
        off += params;
    }

    const uint32_t npts = (uint32_t)(in_sizes[0] / 3);
    const size_t ws_needed = (size_t)(NLVL - NDENSE) * npts * sizeof(v2f);

    if (ws_size >= ws_needed && (npts % FBLK) == 0u) {
        v2f* ws = (v2f*)d_ws;
        // hashed levels 5..15, one kernel each (temporal phasing for L2 residency)
        for (int l = NDENSE; l < NLVL; ++l) {
            hipLaunchKernelGGL(hash_level_kernel2, dim3(npts / 512u), dim3(256), 0, stream,
                               inputs, emb, ws + (size_t)(l - NDENSE) * npts,
                               P.scale[l], P.side[l], P.offset[l]);
        }
        // allow >64 KiB dynamic LDS (host-side attribute set; graph-capture-safe)
        static bool attr_set = [] {
            hipFuncSetAttribute(reinterpret_cast<const void*>(finalize_kernel),
                                hipFuncAttributeMaxDynamicSharedMemorySize, LDS_BYTES);
            return true;
        }();
        (void)attr_set;
        hipLaunchKernelGGL(finalize_kernel, dim3(npts / FBLK), dim3(FBLK), LDS_BYTES, stream,
                           inputs, emb, ws, out, npts, DP);
    } else {
        const uint32_t nblk = (npts + 255u) / 256u;
        hipLaunchKernelGGL(grid_encode_mono, dim3(nblk), dim3(256), 0, stream,
                           inputs, emb, out, npts, P);
    }
}

// Round 8
// 467.223 us; speedup vs baseline: 1.1083x; 1.0671x over previous
//
#include <hip/hip_runtime.h>
#include <cstdint>
#include <cmath>

#define NLVL 16
#define NDENSE 5
#define FBLK 1024u
// Levels 0+1 are contiguous from emb[0]: 4920 + 13824 = 18744 entries.
#define TAB_ENTRIES 18744u
// LDS floats: max(staged table 2*18744+pad, transpose 1024*33=33792) -> 37504 floats
#define LDS_FLOATS 37504u
#define LDS_BYTES (LDS_FLOATS * 4u)   // 150016 B <= 160 KiB

typedef float v2f __attribute__((ext_vector_type(2)));
typedef float v4f __attribute__((ext_vector_type(4)));
typedef float v4f8 __attribute__((ext_vector_type(4), aligned(8)));  // 8B-aligned float4

struct Params {
    float    scale[NLVL];
    uint32_t side[NLVL];
    uint32_t offset[NLVL];
    uint32_t hashed[NLVL];
};

struct DenseParams {
    float    scale[NDENSE];
    uint32_t side[NDENSE];
    uint32_t offset[NDENSE];
};

__device__ __forceinline__ uint32_t umin32(uint32_t a, uint32_t b) { return a < b ? a : b; }

// Hashed-level corner pair: adjacent even/odd pair iff c0a even -> one aligned
// dwordx4 serves both; else predicated v2f for corner b.
// 6 L2 requests/point average — proven floor for the instant-ngp XOR hash
// (odd-c0a x-pairs hash to unrelated lines; y/z pairs never contiguous).
__device__ __forceinline__ void pair_load(const float* __restrict__ embf,
                                          uint32_t ia, uint32_t ib,
                                          v2f& va, v2f& vb) {
    const v4f q = *(const v4f*)(embf + 2u * (ia & ~1u));
    v2f lo; lo.x = q.x; lo.y = q.y;
    v2f hi; hi.x = q.z; hi.y = q.w;
    va = (ia & 1u) ? hi : lo;
    if ((ia ^ ib) > 1u) {
        vb = *(const v2f*)(embf + 2u * ib);   // predicated: only unpaired lanes
    } else {
        vb = (ib & 1u) ? hi : lo;
    }
}

// Dense-level x-pair from GLOBAL: contiguous (ib = ia+1, or clamped = ia).
__device__ __forceinline__ void dense_pair_load(const float* __restrict__ embf,
                                                uint32_t ia, uint32_t clamped,
                                                v2f& va, v2f& vb) {
    const v4f8 q = *(const v4f8*)(embf + 2u * ia);
    va.x = q.x; va.y = q.y;
    v2f hi; hi.x = q.z; hi.y = q.w;
    vb = clamped ? va : hi;
}

// Full per-point hashed-level evaluation (indices + 6 avg gathers + weights).
__device__ __forceinline__ v2f hash_point(const float* __restrict__ embf,
                                          float x, float y, float z,
                                          float scale, uint32_t side, uint32_t off) {
    float p0 = x * scale + 0.5f, p1 = y * scale + 0.5f, p2 = z * scale + 0.5f;
    float fl0 = floorf(p0), fl1 = floorf(p1), fl2 = floorf(p2);
    float f0 = p0 - fl0, f1 = p1 - fl1, f2 = p2 - fl2;
    uint32_t g0 = (uint32_t)fl0, g1 = (uint32_t)fl1, g2 = (uint32_t)fl2;

    const uint32_t smax = side - 1u;
    uint32_t c0a = umin32(g0, smax), c0b = umin32(g0 + 1u, smax);
    uint32_t c1a = umin32(g1, smax), c1b = umin32(g1 + 1u, smax);
    uint32_t c2a = umin32(g2, smax), c2b = umin32(g2 + 1u, smax);

    const uint32_t h1a = c1a * 2654435761u, h1b = c1b * 2654435761u;
    const uint32_t h2a = c2a * 805459861u,  h2b = c2b * 805459861u;
    const uint32_t idx0 = ((c0a ^ h1a ^ h2a) & 0x7FFFFu) + off;
    const uint32_t idx1 = ((c0a ^ h1a ^ h2b) & 0x7FFFFu) + off;
    const uint32_t idx2 = ((c0a ^ h1b ^ h2a) & 0x7FFFFu) + off;
    const uint32_t idx3 = ((c0a ^ h1b ^ h2b) & 0x7FFFFu) + off;
    const uint32_t idx4 = ((c0b ^ h1a ^ h2a) & 0x7FFFFu) + off;
    const uint32_t idx5 = ((c0b ^ h1a ^ h2b) & 0x7FFFFu) + off;
    const uint32_t idx6 = ((c0b ^ h1b ^ h2a) & 0x7FFFFu) + off;
    const uint32_t idx7 = ((c0b ^ h1b ^ h2b) & 0x7FFFFu) + off;

    v2f v0, v1, v2, v3, v4, v5, v6, v7;
    pair_load(embf, idx0, idx4, v0, v4);
    pair_load(embf, idx1, idx5, v1, v5);
    pair_load(embf, idx2, idx6, v2, v6);
    pair_load(embf, idx3, idx7, v3, v7);

    const float w0a = 1.0f - f0, w0b = f0;
    const float w1a = 1.0f - f1, w1b = f1;
    const float w2a = 1.0f - f2, w2b = f2;
    return (w0a * w1a * w2a) * v0 + (w0a * w1a * w2b) * v1
         + (w0a * w1b * w2a) * v2 + (w0a * w1b * w2b) * v3
         + (w0b * w1a * w2a) * v4 + (w0b * w1a * w2b) * v5
         + (w0b * w1b * w2a) * v6 + (w0b * w1b * w2b) * v7;
}

// ---------- Phase kernel: one hashed level, 1 point/thread, cached input loads.
// Measured at the L2 random-request wall (~185 G req/s); more ILP (2 pt/thread,
// round 7) and nt input loads (round 6) both regressed. ----------
__global__ __launch_bounds__(256) void hash_level_kernel(
    const float* __restrict__ in, const float* __restrict__ embf,
    v2f* __restrict__ wsl, float scale, uint32_t side, uint32_t off, uint32_t npts)
{
    const uint32_t i = blockIdx.x * 256u + threadIdx.x;
    if (i >= npts) return;
    const float x = in[3u * i + 0u];
    const float y = in[3u * i + 1u];
    const float z = in[3u * i + 2u];
    const v2f r = hash_point(embf, x, y, z, scale, side, off);
    __builtin_nontemporal_store(r, wsl + i);
}

// ---------- Finalize: LDS-staged levels 0-1, global levels 2-4, ws 5-15 -> out ----------
__global__ __launch_bounds__(1024, 4) void finalize_kernel(
    const float* __restrict__ in, const float* __restrict__ embf,
    const v2f* __restrict__ ws, float* __restrict__ out,
    uint32_t npts, DenseParams P)
{
    extern __shared__ float lds[];
    const uint32_t t = threadIdx.x;
    const uint32_t i = blockIdx.x * FBLK + t;

    // Phase A: stage emb[0 .. TAB_ENTRIES) (levels 0+1, contiguous) into LDS.
    {
        const v4f* src4 = (const v4f*)embf;
        v4f* dst4 = (v4f*)lds;
        #pragma unroll
        for (uint32_t j = 0; j < 10; ++j) {
            const uint32_t k = j * FBLK + t;
            if (k < LDS_FLOATS / 4u) dst4[k] = src4[k];
        }
    }

    const float x = in[3u * i + 0u];
    const float y = in[3u * i + 1u];
    const float z = in[3u * i + 2u];

    __syncthreads();

    float res[32];   // fully static-indexed (unrolled) -> registers

    // dense levels; 0-1 from LDS, 2-4 from global (L2-resident)
    #pragma unroll
    for (int l = 0; l < NDENSE; ++l) {
        const float scale = P.scale[l];
        const uint32_t side = P.side[l];
        const uint32_t off  = P.offset[l];

        float p0 = x * scale + 0.5f, p1 = y * scale + 0.5f, p2 = z * scale + 0.5f;
        float fl0 = floorf(p0), fl1 = floorf(p1), fl2 = floorf(p2);
        float f0 = p0 - fl0, f1 = p1 - fl1, f2 = p2 - fl2;
        uint32_t g0 = (uint32_t)fl0, g1 = (uint32_t)fl1, g2 = (uint32_t)fl2;

        const uint32_t smax = side - 1u;
        uint32_t c0a = umin32(g0, smax);
        const uint32_t clamped = (c0a == smax) ? 1u : 0u;   // c0b == c0a
        uint32_t c1a = umin32(g1, smax), c1b = umin32(g1 + 1u, smax);
        uint32_t c2a = umin32(g2, smax), c2b = umin32(g2 + 1u, smax);

        const uint32_t s2 = side * side;
        const uint32_t ia0 = c0a + c1a * side + c2a * s2 + off;
        const uint32_t ia1 = c0a + c1a * side + c2b * s2 + off;
        const uint32_t ia2 = c0a + c1b * side + c2a * s2 + off;
        const uint32_t ia3 = c0a + c1b * side + c2b * s2 + off;

        v2f v0, v1, v2, v3, v4, v5, v6, v7;
        if (l < 2) {
            v0 = *(const v2f*)(lds + 2u * ia0);
            v4 = clamped ? v0 : *(const v2f*)(lds + 2u * ia0 + 2u);
            v1 = *(const v2f*)(lds + 2u * ia1);
            v5 = clamped ? v1 : *(const v2f*)(lds + 2u * ia1 + 2u);
            v2 = *(const v2f*)(lds + 2u * ia2);
            v6 = clamped ? v2 : *(const v2f*)(lds + 2u * ia2 + 2u);
            v3 = *(const v2f*)(lds + 2u * ia3);
            v7 = clamped ? v3 : *(const v2f*)(lds + 2u * ia3 + 2u);
        } else {
            dense_pair_load(embf, ia0, clamped, v0, v4);
            dense_pair_load(embf, ia1, clamped, v1, v5);
            dense_pair_load(embf, ia2, clamped, v2, v6);
            dense_pair_load(embf, ia3, clamped, v3, v7);
        }

        const float w0a = 1.0f - f0, w0b = f0;
        const float w1a = 1.0f - f1, w1b = f1;
        const float w2a = 1.0f - f2, w2b = f2;
        v2f r = (w0a * w1a * w2a) * v0 + (w0a * w1a * w2b) * v1
              + (w0a * w1b * w2a) * v2 + (w0a * w1b * w2b) * v3
              + (w0b * w1a * w2a) * v4 + (w0b * w1a * w2b) * v5
              + (w0b * w1b * w2a) * v6 + (w0b * w1b * w2b) * v7;
        res[2 * l]     = r.x;
        res[2 * l + 1] = r.y;
    }

    // hashed levels 5..15 from workspace (coalesced)
    #pragma unroll
    for (int l = NDENSE; l < NLVL; ++l) {
        v2f r = __builtin_nontemporal_load(ws + (size_t)(l - NDENSE) * npts + i);
        res[2 * l]     = r.x;
        res[2 * l + 1] = r.y;
    }

    // Phase B: reuse LDS as [1024][33] transpose buffer
    __syncthreads();
    {
        float* row = lds + t * 33u;
        #pragma unroll
        for (int k = 0; k < 32; ++k) row[k] = res[k];   // stride 33: conflict-free
    }
    __syncthreads();

    // coalesced output: block's 128 KB chunk written contiguously
    float* obase = out + (size_t)blockIdx.x * FBLK * 32u;
    #pragma unroll
    for (uint32_t k = 0; k < 8; ++k) {
        const uint32_t f = k * 4096u + t * 4u;          // float idx in chunk
        const uint32_t p = f >> 5, c = f & 31u;
        const float* src = lds + p * 33u + c;
        v4f q; q.x = src[0]; q.y = src[1]; q.z = src[2]; q.w = src[3];
        __builtin_nontemporal_store(q, (v4f*)(obase + f));
    }
}

// ---------- Fallback: monolithic kernel (used if ws too small / odd sizes) ----------
__global__ __launch_bounds__(256) void grid_encode_mono(
    const float* __restrict__ in, const float* __restrict__ emb,
    float* __restrict__ out, uint32_t npts, Params P)
{
    const uint32_t i = blockIdx.x * 256u + threadIdx.x;
    if (i >= npts) return;
    const float x = in[3u * i + 0u], y = in[3u * i + 1u], z = in[3u * i + 2u];
    const v2f* e2 = (const v2f*)emb;
    float* outp = out + (size_t)i * 32u;

    #pragma unroll 1
    for (int l = 0; l < NLVL; ++l) {
        const float scale = P.scale[l];
        const uint32_t side = P.side[l], off = P.offset[l], hashed = P.hashed[l];
        float p0 = x * scale + 0.5f, p1 = y * scale + 0.5f, p2 = z * scale + 0.5f;
        float fl0 = floorf(p0), fl1 = floorf(p1), fl2 = floorf(p2);
        float f0 = p0 - fl0, f1 = p1 - fl1, f2 = p2 - fl2;
        uint32_t g0 = (uint32_t)fl0, g1 = (uint32_t)fl1, g2 = (uint32_t)fl2;
        const uint32_t smax = side - 1u;
        uint32_t c0a = umin32(g0, smax), c0b = umin32(g0 + 1u, smax);
        uint32_t c1a = umin32(g1, smax), c1b = umin32(g1 + 1u, smax);
        uint32_t c2a = umin32(g2, smax), c2b = umin32(g2 + 1u, smax);
        uint32_t idx0, idx1, idx2, idx3, idx4, idx5, idx6, idx7;
        if (hashed) {
            const uint32_t h1a = c1a * 2654435761u, h1b = c1b * 2654435761u;
            const uint32_t h2a = c2a * 805459861u,  h2b = c2b * 805459861u;
            idx0 = ((c0a ^ h1a ^ h2a) & 0x7FFFFu) + off;
            idx1 = ((c0a ^ h1a ^ h2b) & 0x7FFFFu) + off;
            idx2 = ((c0a ^ h1b ^ h2a) & 0x7FFFFu) + off;
            idx3 = ((c0a ^ h1b ^ h2b) & 0x7FFFFu) + off;
            idx4 = ((c0b ^ h1a ^ h2a) & 0x7FFFFu) + off;
            idx5 = ((c0b ^ h1a ^ h2b) & 0x7FFFFu) + off;
            idx6 = ((c0b ^ h1b ^ h2a) & 0x7FFFFu) + off;
            idx7 = ((c0b ^ h1b ^ h2b) & 0x7FFFFu) + off;
        } else {
            const uint32_t s2 = side * side;
            const uint32_t b1a = c1a * side, b1b = c1b * side;
            const uint32_t b2a = c2a * s2,   b2b = c2b * s2;
            idx0 = (c0a + b1a + b2a) + off; idx1 = (c0a + b1a + b2b) + off;
            idx2 = (c0a + b1b + b2a) + off; idx3 = (c0a + b1b + b2b) + off;
            idx4 = (c0b + b1a + b2a) + off; idx5 = (c0b + b1a + b2b) + off;
            idx6 = (c0b + b1b + b2a) + off; idx7 = (c0b + b1b + b2b) + off;
        }
        const v2f v0 = e2[idx0], v1 = e2[idx1], v2 = e2[idx2], v3 = e2[idx3];
        const v2f v4 = e2[idx4], v5 = e2[idx5], v6 = e2[idx6], v7 = e2[idx7];
        const float w0a = 1.0f - f0, w0b = f0;
        const float w1a = 1.0f - f1, w1b = f1;
        const float w2a = 1.0f - f2, w2b = f2;
        v2f r = (w0a*w1a*w2a) * v0 + (w0a*w1a*w2b) * v1 + (w0a*w1b*w2a) * v2 + (w0a*w1b*w2b) * v3
              + (w0b*w1a*w2a) * v4 + (w0b*w1a*w2b) * v5 + (w0b*w1b*w2a) * v6 + (w0b*w1b*w2b) * v7;
        *(v2f*)(outp + 2 * l) = r;
    }
}

extern "C" void kernel_launch(void* const* d_in, const int* in_sizes, int n_in,
                              void* d_out, int out_size, void* d_ws, size_t ws_size,
                              hipStream_t stream) {
    const float* inputs = (const float*)d_in[0];
    const float* emb    = (const float*)d_in[1];
    float* out          = (float*)d_out;

    // Mirror GridEncoder.__init__ level config in double precision (matches numpy).
    Params P;
    DenseParams DP;
    const double PLS = exp2(log2(2048.0 / 16.0) / 15.0);
    uint64_t off = 0;
    for (int l = 0; l < NLVL; ++l) {
        const double s = 16.0 * pow(PLS, (double)l);
        const uint32_t side = (uint32_t)ceil(s) + 1u;
        const uint64_t s3 = (uint64_t)side * side * side;
        uint64_t params = s3 < (1ull << 19) ? s3 : (1ull << 19);
        params = (params + 7ull) / 8ull * 8ull;
        P.scale[l]  = (float)(s - 1.0);
        P.side[l]   = side;
        P.offset[l] = (uint32_t)off;
        P.hashed[l] = (s3 > params) ? 1u : 0u;
        if (l < NDENSE) { DP.scale[l] = P.scale[l]; DP.side[l] = P.side[l]; DP.offset[l] = P.offset[l]; }
        off += params;
    }

    const uint32_t npts = (uint32_t)(in_sizes[0] / 3);
    const size_t ws_needed = (size_t)(NLVL - NDENSE) * npts * sizeof(v2f);

    if (ws_size >= ws_needed && (npts % FBLK) == 0u) {
        v2f* ws = (v2f*)d_ws;
        const uint32_t nblk = npts / 256u;
        // hashed levels 5..15, one kernel each (temporal phasing: one 4-MB table
        // resident per XCD-L2 at a time)
        for (int l = NDENSE; l < NLVL; ++l) {
            hipLaunchKernelGGL(hash_level_kernel, dim3(nblk), dim3(256), 0, stream,
                               inputs, emb, ws + (size_t)(l - NDENSE) * npts,
                               P.scale[l], P.side[l], P.offset[l], npts);
        }
        // allow >64 KiB dynamic LDS (host-side attribute set; graph-capture-safe)
        static bool attr_set = [] {
            hipFuncSetAttribute(reinterpret_cast<const void*>(finalize_kernel),
                                hipFuncAttributeMaxDynamicSharedMemorySize, LDS_BYTES);
            return true;
        }();
        (void)attr_set;
        hipLaunchKernelGGL(finalize_kernel, dim3(npts / FBLK), dim3(FBLK), LDS_BYTES, stream,
                           inputs, emb, ws, out, npts, DP);
    } else {
        const uint32_t nblk = (npts + 255u) / 256u;
        hipLaunchKernelGGL(grid_encode_mono, dim3(nblk), dim3(256), 0, stream,
                           inputs, emb, out, npts, P);
    }
}